// Round 1
// baseline (990.312 us; speedup 1.0000x reference)
//
#include <hip/hip_runtime.h>

// Problem constants
#define B_  8
#define C_  32
#define U_  5
#define V_  5
#define H_  64
#define W_  64
#define OC_ 8    // out channels per branch

// x strides (floats): [B][C][U][V][H][W]
#define SW  1
#define SH  (W_)                 // 64
#define SV  (H_ * W_)            // 4096
#define SU  (V_ * SV)            // 20480
#define SC  (U_ * SU)            // 102400
#define SB  (C_ * SC)            // 3276800
// out: [B][32][U][V][H][W] -> same SC per channel, same SB per batch

#define NW   6912                // weights per branch: 8*32*27

// LDS weight layout: [c][t0][t1][oc][t2]  (24 contiguous floats per (c,t0,t1))
__device__ __forceinline__ void stage_weights(const float* __restrict__ wsrc,
                                              const float* __restrict__ bsrc,
                                              const float* __restrict__ asrc,
                                              float* wlds, float* blds, float* alds,
                                              int tid) {
    __syncthreads();   // previous branch finished reading LDS
    for (int e = tid; e < NW; e += 256) {
        int t2 = e % 3;
        int t1 = (e / 3) % 3;
        int t0 = (e / 9) % 3;
        int c  = (e / 27) % C_;
        int oc = e / (27 * C_);
        wlds[(((c * 3 + t0) * 3 + t1) * OC_ + oc) * 3 + t2] = wsrc[e];
    }
    if (tid < OC_) blds[tid] = bsrc[tid];
    if (tid == 0)  *alds = asrc[0];
    __syncthreads();
}

// BR=0: uvx  taps (du=t0, dv=t1, dh=t2, dw=0)
// BR=1: uvy  taps (du=t0, dv=t1, dh=0,  dw=t2)
// BR=2: uxy  taps (du=t0, dv=0,  dh=t1, dw=t2)
// BR=3: vxy  taps (du=0,  dv=t0, dh=t1, dw=t2)
template<int BR>
__device__ __forceinline__ void branch_compute(const float* __restrict__ xb,  // x + b*SB
                                               const float* __restrict__ wl,
                                               const float* __restrict__ bl,
                                               float aval,
                                               int u, int v, int h, int w0q,
                                               float* __restrict__ outp)       // out + b*SB + u*SU + v*SV + h*SH + w0q
{
    float acc[OC_][4];
#pragma unroll
    for (int o = 0; o < OC_; ++o) {
        acc[o][0] = 0.f; acc[o][1] = 0.f; acc[o][2] = 0.f; acc[o][3] = 0.f;
    }

    for (int c = 0; c < C_; ++c) {
        const float* xc = xb + (size_t)c * SC;
#pragma unroll
        for (int t0 = 0; t0 < 3; ++t0) {
            const int d0   = (BR == 3 ? v : u) + t0 - 1;
            const int lim0 = (BR == 3 ? V_ : U_);
            if (d0 < 0 || d0 >= lim0) continue;               // wave-uniform
            const float* x0 = xc + (size_t)d0 * (BR == 3 ? SV : SU);
#pragma unroll
            for (int t1 = 0; t1 < 3; ++t1) {
                const float* wg = wl + ((c * 3 + t0) * 3 + t1) * (OC_ * 3);
                if (BR == 0 || BR == 1) {
                    const int d1 = v + t1 - 1;
                    if (d1 < 0 || d1 >= V_) continue;         // wave-uniform
                    const float* x1 = x0 + (size_t)d1 * SV;
                    if (BR == 0) {
                        // 3 h-rows, 4 w each (dw = 0)
                        float xv[3][4];
#pragma unroll
                        for (int t2 = 0; t2 < 3; ++t2) {
                            const int hh = h + t2 - 1;
                            const bool ok = (hh >= 0) && (hh < H_);
                            const float4 m = ok
                                ? *(const float4*)(x1 + (ok ? hh : 0) * SH + w0q)
                                : make_float4(0.f, 0.f, 0.f, 0.f);
                            xv[t2][0] = m.x; xv[t2][1] = m.y; xv[t2][2] = m.z; xv[t2][3] = m.w;
                        }
#pragma unroll
                        for (int o = 0; o < OC_; ++o)
#pragma unroll
                            for (int t2 = 0; t2 < 3; ++t2) {
                                const float wv = wg[o * 3 + t2];
#pragma unroll
                                for (int ww = 0; ww < 4; ++ww)
                                    acc[o][ww] += xv[t2][ww] * wv;
                            }
                    } else {
                        // one row at h, 6 w values (dw = -1..1)
                        const float* xr = x1 + (size_t)h * SH;
                        float r[6];
                        r[0] = (w0q > 0) ? xr[w0q - 1] : 0.f;
                        const float4 m = *(const float4*)(xr + w0q);
                        r[1] = m.x; r[2] = m.y; r[3] = m.z; r[4] = m.w;
                        r[5] = (w0q + 4 < W_) ? xr[w0q + 4] : 0.f;
#pragma unroll
                        for (int o = 0; o < OC_; ++o)
#pragma unroll
                            for (int t2 = 0; t2 < 3; ++t2) {
                                const float wv = wg[o * 3 + t2];
#pragma unroll
                                for (int ww = 0; ww < 4; ++ww)
                                    acc[o][ww] += r[ww + t2] * wv;
                            }
                    }
                } else {
                    // BR==2: x[c][d0(u)][v][hh][w] ; BR==3: x[c][u][d0(v)][hh][w]
                    const int hh = h + t1 - 1;
                    const bool ok = (hh >= 0) && (hh < H_);
                    const float* xr = x0 + (BR == 2 ? (size_t)v * SV : (size_t)u * SU)
                                         + (size_t)(ok ? hh : 0) * SH;
                    float r[6];
                    r[0] = (ok && w0q > 0) ? xr[w0q - 1] : 0.f;
                    const float4 m = ok ? *(const float4*)(xr + w0q)
                                        : make_float4(0.f, 0.f, 0.f, 0.f);
                    r[1] = m.x; r[2] = m.y; r[3] = m.z; r[4] = m.w;
                    r[5] = (ok && (w0q + 4 < W_)) ? xr[w0q + 4] : 0.f;
#pragma unroll
                    for (int o = 0; o < OC_; ++o)
#pragma unroll
                        for (int t2 = 0; t2 < 3; ++t2) {
                            const float wv = wg[o * 3 + t2];
#pragma unroll
                            for (int ww = 0; ww < 4; ++ww)
                                acc[o][ww] += r[ww + t2] * wv;
                        }
                }
            }
        }
    }

    // epilogue: bias + PReLU + store (branch BR owns out channels BR*8 .. BR*8+7)
#pragma unroll
    for (int o = 0; o < OC_; ++o) {
        const float bv = bl[o];
        float4 y;
        float t;
        t = acc[o][0] + bv; y.x = (t >= 0.f) ? t : aval * t;
        t = acc[o][1] + bv; y.y = (t >= 0.f) ? t : aval * t;
        t = acc[o][2] + bv; y.z = (t >= 0.f) ? t : aval * t;
        t = acc[o][3] + bv; y.w = (t >= 0.f) ? t : aval * t;
        *(float4*)(outp + (size_t)(BR * OC_ + o) * SC) = y;
    }
}

__global__ __launch_bounds__(256, 4)
void fe_block3d_kernel(const float* __restrict__ x,
                       const float* __restrict__ w0, const float* __restrict__ b0, const float* __restrict__ a0,
                       const float* __restrict__ w1, const float* __restrict__ b1, const float* __restrict__ a1,
                       const float* __restrict__ w2, const float* __restrict__ b2, const float* __restrict__ a2,
                       const float* __restrict__ w3, const float* __restrict__ b3, const float* __restrict__ a3,
                       float* __restrict__ out)
{
    __shared__ float wlds[NW];
    __shared__ float blds[OC_];
    __shared__ float alds;

    const int tid  = threadIdx.x;
    const int blk  = blockIdx.x;            // ((b*U+u)*V+v)*4 + hblk
    const int hblk = blk & 3;
    int t = blk >> 2;
    const int v = t % V_; t /= V_;
    const int u = t % U_; t /= U_;
    const int b = t;

    const int h   = hblk * 16 + (tid >> 4);
    const int w0q = (tid & 15) * 4;

    const float* xb   = x + (size_t)b * SB;
    float* outp = out + (size_t)b * SB + (size_t)u * SU + (size_t)v * SV
                      + (size_t)h * SH + w0q;

    stage_weights(w0, b0, a0, wlds, blds, &alds, tid);
    branch_compute<0>(xb, wlds, blds, alds, u, v, h, w0q, outp);

    stage_weights(w1, b1, a1, wlds, blds, &alds, tid);
    branch_compute<1>(xb, wlds, blds, alds, u, v, h, w0q, outp);

    stage_weights(w2, b2, a2, wlds, blds, &alds, tid);
    branch_compute<2>(xb, wlds, blds, alds, u, v, h, w0q, outp);

    stage_weights(w3, b3, a3, wlds, blds, &alds, tid);
    branch_compute<3>(xb, wlds, blds, alds, u, v, h, w0q, outp);
}

extern "C" void kernel_launch(void* const* d_in, const int* in_sizes, int n_in,
                              void* d_out, int out_size, void* d_ws, size_t ws_size,
                              hipStream_t stream) {
    const float* x  = (const float*)d_in[0];
    const float* w0 = (const float*)d_in[1];
    const float* b0 = (const float*)d_in[2];
    const float* a0 = (const float*)d_in[3];
    const float* w1 = (const float*)d_in[4];
    const float* b1 = (const float*)d_in[5];
    const float* a1 = (const float*)d_in[6];
    const float* w2 = (const float*)d_in[7];
    const float* b2 = (const float*)d_in[8];
    const float* a2 = (const float*)d_in[9];
    const float* w3 = (const float*)d_in[10];
    const float* b3 = (const float*)d_in[11];
    const float* a3 = (const float*)d_in[12];
    float* out = (float*)d_out;

    const int grid = B_ * U_ * V_ * 4;   // 800 blocks
    fe_block3d_kernel<<<grid, 256, 0, stream>>>(
        x, w0, b0, a0, w1, b1, a1, w2, b2, a2, w3, b3, a3, out);
}

// Round 2
// 424.301 us; speedup vs baseline: 2.3340x; 2.3340x over previous
//
#include <hip/hip_runtime.h>

// ---------------- problem constants ----------------
#define B_  8
#define C_  32
#define U_  5
#define V_  5
#define H_  64
#define W_  64

// x / out strides (fp32 elements): [B][32][U][V][H][W]
#define SV_ 4096
#define SU_ 20480
#define SC_ 102400
#define SB_ 3276800

// xT (bf16) element strides: [b][u][v][h][w][c], c contiguous
#define XT_ROW 2048        // one (h) row = 64 w * 32 c

// workspace layout (bytes): [0, 52428800) = xT bf16 ; [52428800, +55296) = B-frag table
#define BT_OFF 52428800ull
// ws_size requirement: ~50.1 MiB

typedef short bf16x8 __attribute__((ext_vector_type(8)));
typedef float f32x4 __attribute__((ext_vector_type(4)));

__device__ __forceinline__ unsigned short f2bf(float f) {
    unsigned int u = __builtin_bit_cast(unsigned int, f);
    u = (u + 0x7FFFu + ((u >> 16) & 1u)) >> 16;   // round-to-nearest-even
    return (unsigned short)u;
}

__device__ __forceinline__ f32x4 mfma16(bf16x8 a, bf16x8 b, f32x4 c) {
    return __builtin_amdgcn_mfma_f32_16x16x32_bf16(a, b, c, 0, 0, 0);
}

// ---------------- K1: x [B,C,U,V,H,W] fp32 -> xT [b,u,v,h,w,c] bf16 ----------------
__global__ __launch_bounds__(256)
void k_transpose(const float* __restrict__ x, unsigned short* __restrict__ xT)
{
    __shared__ unsigned short tl[64][33];   // [w][c], padded
    const int tid = threadIdx.x;
    int blk = blockIdx.x;
    const int h = blk & 63; blk >>= 6;
    const int v = blk % 5; blk /= 5;
    const int u = blk % 5;
    const int b = blk / 5;

    const float* src = x + (size_t)b * SB_ + (size_t)u * SU_ + (size_t)v * SV_ + h * 64;
    const int c  = tid >> 3;          // 0..31
    const int w8 = (tid & 7) * 8;     // 0..56
    const float4 A  = *(const float4*)(src + (size_t)c * SC_ + w8);
    const float4 Bv = *(const float4*)(src + (size_t)c * SC_ + w8 + 4);
    tl[w8 + 0][c] = f2bf(A.x);  tl[w8 + 1][c] = f2bf(A.y);
    tl[w8 + 2][c] = f2bf(A.z);  tl[w8 + 3][c] = f2bf(A.w);
    tl[w8 + 4][c] = f2bf(Bv.x); tl[w8 + 5][c] = f2bf(Bv.y);
    tl[w8 + 6][c] = f2bf(Bv.z); tl[w8 + 7][c] = f2bf(Bv.w);
    __syncthreads();
    const int w  = tid >> 2;
    const int cb = (tid & 3) * 8;
    uint4 o;
    o.x = (unsigned)tl[w][cb + 0] | ((unsigned)tl[w][cb + 1] << 16);
    o.y = (unsigned)tl[w][cb + 2] | ((unsigned)tl[w][cb + 3] << 16);
    o.z = (unsigned)tl[w][cb + 4] | ((unsigned)tl[w][cb + 5] << 16);
    o.w = (unsigned)tl[w][cb + 6] | ((unsigned)tl[w][cb + 7] << 16);
    unsigned short* dst = xT + (size_t)((b * 25 + u * 5 + v) * 64 + h) * XT_ROW;
    ((uint4*)dst)[tid] = o;
}

// ---------------- K2: weights fp32 -> compact B-frag table bf16 ----------------
// frag f = br*27 + t0*9 + t1*3 + t2 ; layout per frag: [oc(8)][c(32)] bf16 = 512 B
__global__ __launch_bounds__(256)
void k_weights(const float* __restrict__ w0, const float* __restrict__ w1,
               const float* __restrict__ w2, const float* __restrict__ w3,
               unsigned short* __restrict__ btab)
{
    const int tid = threadIdx.x;
    const int n = tid >> 5;    // oc 0..7
    const int k = tid & 31;    // c
    for (int br = 0; br < 4; ++br) {
        const float* wp = (br == 0) ? w0 : (br == 1) ? w1 : (br == 2) ? w2 : w3;
        for (int tap = 0; tap < 27; ++tap) {
            const int f = br * 27 + tap;
            btab[(size_t)f * 256 + n * 32 + k] = f2bf(wp[(size_t)n * 864 + k * 27 + tap]);
        }
    }
}

// ---------------- K3: main MFMA kernel ----------------
// block = (b, u, v, 2 h-rows); 4 waves = 4 w-tiles of 16.
// LDS x-tile: 3 v-planes x 4 h-rows x 66 px x 32c bf16 (zero halos) = 50688 B
// MFMA: A = W[oc(16,pad)][c(32)], B = x[c(32)][w(16)], D[oc][w]
//   A-frag lane: oc = lane&15 (&7 replicated), c = (lane>>4)*8+j
//   B-frag lane: w  = lane&15,                 c = (lane>>4)*8+j
//   D lane:      w  = lane&15,                 oc = (lane>>4)*4+reg
__global__ __launch_bounds__(256)
void k_main(const unsigned short* __restrict__ xT,
            const unsigned short* __restrict__ btabu,
            const float* __restrict__ bb0, const float* __restrict__ aa0,
            const float* __restrict__ bb1, const float* __restrict__ aa1,
            const float* __restrict__ bb2, const float* __restrict__ aa2,
            const float* __restrict__ bb3, const float* __restrict__ aa3,
            float* __restrict__ out)
{
    __shared__ uint4 xlds[3168];   // 12 rows * 264 uint4 (4224 B/row)

    const int tid = threadIdx.x;
    int blk = blockIdx.x;
    const int hs = blk & 31; blk >>= 5;
    const int v = blk % 5; blk /= 5;
    const int u = blk % 5;
    const int b = blk / 5;
    const int h0 = hs * 2;

    const int lane = tid & 63;
    const int n = lane & 15;       // w-pixel col (B/x, D) ; oc&15 for A/W frag
    const int q = lane >> 4;
    const int w0 = (tid >> 6) * 16;

    f32x4 acc[4][2];
#pragma unroll
    for (int i = 0; i < 4; ++i)
#pragma unroll
        for (int j = 0; j < 2; ++j) acc[i][j] = (f32x4)0.f;

    const char* bt = (const char*)btabu;
    const int aoff_base = (w0 + n) * 64 + q * 16;

    for (int du = 0; du < 3; ++du) {
        const int up = u + du - 1;
        const bool u_ok = (up >= 0) && (up < 5);
        __syncthreads();
        if (u_ok) {
            const uint4* xt4 = (const uint4*)xT;
            const uint4 z = {0u, 0u, 0u, 0u};
#pragma unroll
            for (int rr = 0; rr < 12; ++rr) {
                const int vp = v + (rr >> 2) - 1;
                const int hp = h0 + (rr & 3) - 1;
                uint4 val = z;
                if (vp >= 0 && vp < 5 && hp >= 0 && hp < 64)
                    val = xt4[(size_t)((b * 25 + up * 5 + vp) * 64 + hp) * 256 + tid];
                xlds[rr * 264 + 4 + tid] = val;
                if (tid < 4)    xlds[rr * 264 + tid] = z;        // w = -1 halo
                if (tid >= 252) xlds[rr * 264 + 8 + tid] = z;    // w = 64 halo
            }
        }
        __syncthreads();
        if (!u_ok) continue;

        const char* X = (const char*)xlds;
        auto AF = [&](int dv, int row, int dw) -> bf16x8 {
            return *(const bf16x8*)(X + dv * 16896 + row * 4224 + dw * 64 + aoff_base);
        };
        auto WF = [&](int f) -> bf16x8 {
            return *(const bf16x8*)(bt + f * 512 + (n & 7) * 64 + q * 16);
        };

        // br0: uvx (conv u,v,h): taps (du, dv, dh); w neutral (dw=1)
#pragma unroll
        for (int dv = 0; dv < 3; ++dv) {
            const int fb = du * 9 + dv * 3;
            bf16x8 Wf0 = WF(fb + 0), Wf1 = WF(fb + 1), Wf2 = WF(fb + 2);
#pragma unroll
            for (int hh = 0; hh < 2; ++hh) {
                acc[0][hh] = mfma16(Wf0, AF(dv, hh + 0, 1), acc[0][hh]);
                acc[0][hh] = mfma16(Wf1, AF(dv, hh + 1, 1), acc[0][hh]);
                acc[0][hh] = mfma16(Wf2, AF(dv, hh + 2, 1), acc[0][hh]);
            }
        }
        // br1: uvy (conv u,v,w): taps (du, dv, dw); row = hh+1
#pragma unroll
        for (int dv = 0; dv < 3; ++dv) {
            const int fb = 27 + du * 9 + dv * 3;
            bf16x8 Wf0 = WF(fb + 0), Wf1 = WF(fb + 1), Wf2 = WF(fb + 2);
#pragma unroll
            for (int hh = 0; hh < 2; ++hh) {
                acc[1][hh] = mfma16(Wf0, AF(dv, hh + 1, 0), acc[1][hh]);
                acc[1][hh] = mfma16(Wf1, AF(dv, hh + 1, 1), acc[1][hh]);
                acc[1][hh] = mfma16(Wf2, AF(dv, hh + 1, 2), acc[1][hh]);
            }
        }
        // br2: uxy (conv u,h,w): taps (du, dh, dw); plane = v (dv=1)
#pragma unroll
        for (int dh = 0; dh < 3; ++dh) {
            const int fb = 54 + du * 9 + dh * 3;
            bf16x8 Wf0 = WF(fb + 0), Wf1 = WF(fb + 1), Wf2 = WF(fb + 2);
#pragma unroll
            for (int hh = 0; hh < 2; ++hh) {
                acc[2][hh] = mfma16(Wf0, AF(1, hh + dh, 0), acc[2][hh]);
                acc[2][hh] = mfma16(Wf1, AF(1, hh + dh, 1), acc[2][hh]);
                acc[2][hh] = mfma16(Wf2, AF(1, hh + dh, 2), acc[2][hh]);
            }
        }
        // br3: vxy (conv v,h,w): taps (dv, dh, dw); only at du==1 (u'=u)
        if (du == 1) {
#pragma unroll
            for (int dv = 0; dv < 3; ++dv)
#pragma unroll
                for (int dh = 0; dh < 3; ++dh) {
                    const int fb = 81 + dv * 9 + dh * 3;
                    bf16x8 Wf0 = WF(fb + 0), Wf1 = WF(fb + 1), Wf2 = WF(fb + 2);
#pragma unroll
                    for (int hh = 0; hh < 2; ++hh) {
                        acc[3][hh] = mfma16(Wf0, AF(dv, hh + dh, 0), acc[3][hh]);
                        acc[3][hh] = mfma16(Wf1, AF(dv, hh + dh, 1), acc[3][hh]);
                        acc[3][hh] = mfma16(Wf2, AF(dv, hh + dh, 2), acc[3][hh]);
                    }
                }
        }
    }

    // ---------------- epilogue: bias + PReLU + store ----------------
    const float alph0 = aa0[0], alph1 = aa1[0], alph2 = aa2[0], alph3 = aa3[0];
    float* op = out + (size_t)b * SB_ + (size_t)u * SU_ + (size_t)v * SV_ + w0 + n;
    const bool act = (q < 2);
#pragma unroll
    for (int br = 0; br < 4; ++br) {
        const float* bp = (br == 0) ? bb0 : (br == 1) ? bb1 : (br == 2) ? bb2 : bb3;
        const float alph = (br == 0) ? alph0 : (br == 1) ? alph1 : (br == 2) ? alph2 : alph3;
        const f32x4 bv = *(const f32x4*)(bp + (q & 1) * 4);   // bias[oc] for oc = q*4+r
#pragma unroll
        for (int hh = 0; hh < 2; ++hh) {
#pragma unroll
            for (int r = 0; r < 4; ++r) {
                float val = acc[br][hh][r] + bv[r];
                val = (val >= 0.f) ? val : alph * val;
                if (act)
                    op[(size_t)(br * 8 + q * 4 + r) * SC_ + (size_t)(h0 + hh) * 64] = val;
            }
        }
    }
}

extern "C" void kernel_launch(void* const* d_in, const int* in_sizes, int n_in,
                              void* d_out, int out_size, void* d_ws, size_t ws_size,
                              hipStream_t stream) {
    const float* x  = (const float*)d_in[0];
    const float* w0 = (const float*)d_in[1];
    const float* b0 = (const float*)d_in[2];
    const float* a0 = (const float*)d_in[3];
    const float* w1 = (const float*)d_in[4];
    const float* b1 = (const float*)d_in[5];
    const float* a1 = (const float*)d_in[6];
    const float* w2 = (const float*)d_in[7];
    const float* b2 = (const float*)d_in[8];
    const float* a2 = (const float*)d_in[9];
    const float* w3 = (const float*)d_in[10];
    const float* b3 = (const float*)d_in[11];
    const float* a3 = (const float*)d_in[12];
    float* out = (float*)d_out;

    unsigned short* xT = (unsigned short*)d_ws;
    unsigned short* bt = (unsigned short*)((char*)d_ws + BT_OFF);

    k_transpose<<<B_ * U_ * V_ * H_, 256, 0, stream>>>(x, xT);          // 12800 blocks
    k_weights<<<1, 256, 0, stream>>>(w0, w1, w2, w3, bt);
    k_main<<<B_ * U_ * V_ * (H_ / 2), 256, 0, stream>>>(                // 6400 blocks
        xT, bt, b0, a0, b1, a1, b2, a2, b3, a3, out);
}